// Round 5
// baseline (195.128 us; speedup 1.0000x reference)
//
#include <hip/hip_runtime.h>
#include <hip/hip_bf16.h>

// Problem constants
#define B_   2
#define C_   32
#define D_   16
#define HW_  4096
#define CK_  4
#define E_   64    // CK_*D_  (qk dim)
#define M_   512   // C_*D_   (v dim)
#define JC_  4     // j-split factor (flash split-K)

typedef __attribute__((ext_vector_type(8)))  short bf16x8;
typedef __attribute__((ext_vector_type(16))) float f32x16;
typedef __attribute__((ext_vector_type(2)))  unsigned int u32x2;

union U4 { unsigned int u[4]; bf16x8 v; };

__device__ __forceinline__ short f2bf(float f) {
    __hip_bfloat16 h = __float2bfloat16(f);
    return *reinterpret_cast<short*>(&h);
}
__device__ __forceinline__ unsigned short f2bfu(float f) {
    __hip_bfloat16 h = __float2bfloat16(f);
    return *reinterpret_cast<unsigned short*>(&h);
}

// ---------------------------------------------------------------------------
// Kernel 1: MFMA projections (folded-prep version, harness-verified R12).
// ---------------------------------------------------------------------------
__global__ __launch_bounds__(256) void proj_kernel(
    const float* __restrict__ x,
    const float* __restrict__ Wk, const float* __restrict__ bk,
    const float* __restrict__ Wq, const float* __restrict__ bq,
    const float* __restrict__ Wv, const float* __restrict__ bv,
    short* __restrict__ xk, short* __restrict__ xq,
    __hip_bfloat16* __restrict__ v)
{
    __shared__ short s_k[32*16], s_q[32*16];   // [p 32][w*4+o' 16]
    const int t    = threadIdx.x;
    const int lane = t & 63;
    const int w    = t >> 6;
    const int h    = lane >> 5;
    const int c    = lane & 31;

    const int pt = blockIdx.x & 127;
    const int dg = (blockIdx.x >> 7) & 3;
    const int b  = blockIdx.x >> 9;
    const int d  = dg*4 + w;
    const int p0 = pt*32;

    bf16x8 af[2][2];
    #pragma unroll
    for (int s = 0; s < 2; ++s) {
        const float* wv = Wv + c*C_ + s*16 + h*8;
        #pragma unroll
        for (int k = 0; k < 8; ++k) af[0][s][k] = f2bf(wv[k]);
        const float* wu = (c < 4) ? (Wk + c*C_ + s*16 + h*8)
                        : (c < 8) ? (Wq + (c-4)*C_ + s*16 + h*8) : nullptr;
        #pragma unroll
        for (int k = 0; k < 8; ++k) af[1][s][k] = f2bf(wu ? wu[k] : 0.f);
    }

    U4 xb[2];
    #pragma unroll
    for (int s = 0; s < 2; ++s) {
        #pragma unroll
        for (int j = 0; j < 4; ++j) {
            int c0 = s*16 + h*8 + 2*j;
            union { float f; unsigned int u; } ua, ub;
            ua.f = x[(((size_t)(b*C_ + c0  )*D_ + d)*HW_) + p0 + c];
            ub.f = x[(((size_t)(b*C_ + c0+1)*D_ + d)*HW_) + p0 + c];
            xb[s].u[j] = __builtin_amdgcn_perm(ub.u, ua.u, 0x07060302);
        }
    }

    f32x16 a0, a1;
    #pragma unroll
    for (int r = 0; r < 16; ++r) { a0[r] = 0.f; a1[r] = 0.f; }
    #pragma unroll
    for (int s = 0; s < 2; ++s) {
        a0 = __builtin_amdgcn_mfma_f32_32x32x16_bf16(af[0][s], xb[s].v, a0, 0, 0, 0);
        a1 = __builtin_amdgcn_mfma_f32_32x32x16_bf16(af[1][s], xb[s].v, a1, 0, 0, 0);
    }

    #pragma unroll
    for (int r = 0; r < 16; ++r) {
        int o = (r & 3) + 8*(r >> 2) + 4*h;
        v[((size_t)b*M_ + (o*D_ + d))*HW_ + p0 + c] = __float2bfloat16(a0[r] + bv[o]);
    }

    #pragma unroll
    for (int r = 0; r < 4; ++r) {
        if (h == 0) s_k[c*16 + w*4 + r] = f2bf(a1[r] + bk[r]);
        else        s_q[c*16 + w*4 + r] = f2bf(a1[r] + bq[r]);
    }
    __syncthreads();

    const int p = t >> 3, seg = t & 7;
    size_t gb = ((size_t)b*HW_ + p0 + p)*E_ + dg*16 + seg*2;
    *(unsigned int*)(xk + gb) = *(const unsigned int*)(&s_k[p*16 + seg*2]);
    *(unsigned int*)(xq + gb) = *(const unsigned int*)(&s_q[p*16 + seg*2]);
}

// ---------------------------------------------------------------------------
// Kernel 2: flash attention, split-K (JC_=4).
//  R13: producer/consumer restructure to halve the mg-redundant QK^T work.
//  Block = 512 thr (8 waves) covering 128 i x 256 m (mgp = m-half).
//   - waves 0-3 (wm=0, "producers"): ST (4 MFMA) + exp/pack + permlane for
//     i-tile wi — computed ONCE per (ig,jc,mgp... shared by both m-halves
//     within the block via an LDS P-buffer (a2 operand bits, bf16).
//   - waves 4-7 (wm=1, "consumers"): pre-read V frags during ST phase, then
//     PV from the shared P. ST redundancy x4 -> x2; exp & XQ-stage halved.
//  Phase split: raw s_barrier (producer lgkmcnt(0) drain before it) so the
//  global_load_lds prefetch is NOT drained mid-iter; the iter-end
//  __syncthreads drains vmcnt with full-iter cover (R7-lineage behavior).
//  Staging swizzles byte-identical to R7. Grid 512 = 2 blocks/CU (reg-cap).
//  jc-siblings share blockIdx&7 -> same XCD (L2 locality for V-half).
// ---------------------------------------------------------------------------
__device__ __forceinline__ void load_lds16(const short* g, short* l) {
    __builtin_amdgcn_global_load_lds((const __attribute__((address_space(1))) void*)g,
                                     (__attribute__((address_space(3))) void*)l,
                                     16, 0, 0);
}

__global__ __launch_bounds__(512, 4) void attn_kernel(
    const short* __restrict__ xk_, const short* __restrict__ xq_,
    const short* __restrict__ v_,
    unsigned short* __restrict__ Op, float* __restrict__ lw)
{
    __shared__ short s_xq[2][2048];          // XQ tile: 32 j x 64 e      (8 KB)
    __shared__ short s_v [2][8192];          // V  tile: 256 m x 32 j     (32 KB)
    __shared__ short s_p [4][1024];          // P operand per i-tile      (8 KB)

    const int t    = threadIdx.x;
    const int lane = t & 63;
    const int w    = t >> 6;                 // 0..7
    const int wm   = w >> 2;                 // 0 = producer, 1 = consumer (m-half)
    const int wi   = w & 3;                  // i-tile within block
    const int h    = lane >> 5;
    const int c    = lane & 31;
    const int q    = (lane >> 2) & 1;        // P-buffer slot swizzle bit

    const int cls  = blockIdx.x & 7;         // XCD class = (b, mgp, ig&1)
    const int b    = cls >> 2;
    const int mgp  = (cls >> 1) & 1;
    const int igl  = cls & 1;
    const int rest = blockIdx.x >> 3;        // 0..63
    const int ig   = (rest & 15)*2 + igl;    // 0..31
    const int jc   = rest >> 4;              // 0..3
    const int i0   = ig*128 + wi*32;         // wave's 32-row i-tile
    const int jbase = jc*(HW_/JC_);          // 1024-wide j chunk

    const short* xk_g = xk_ + (size_t)b*HW_*E_;
    const short* xq_g = xq_ + (size_t)b*HW_*E_;
    const short* v_g  = v_  + (size_t)b*M_*HW_ + (size_t)mgp*256*HW_;

    // XK B-frags (producers only): kb[s] = XK[i0+c][e = s*16 + h*8 ..+7]
    bf16x8 kb[4];
    if (wm == 0) {
        #pragma unroll
        for (int s = 0; s < 4; ++s)
            kb[s] = *(const bf16x8*)(xk_g + (size_t)(i0 + c)*E_ + s*16 + h*8);
    }

    f32x16 acc[4];
    #pragma unroll
    for (int mt = 0; mt < 4; ++mt)
        #pragma unroll
        for (int r = 0; r < 16; ++r) acc[mt][r] = 0.f;
    float lp = 0.f;

    // ---- staging (R7 swizzles; producers: XQ, consumers: V 256 rows) ----
    auto stage = [&](int buf, int j0) {
        if (wm == 0) {
            int r_ = wi*8 + (lane>>3), cc = (lane&7) ^ (r_&7);
            load_lds16(xq_g + (size_t)(j0 + r_)*E_ + cc*8, &s_xq[buf][wi*512]);
        } else {
            #pragma unroll
            for (int k = 0; k < 4; ++k) {
                int r0 = wi*64 + k*16;
                int r_ = r0 + (lane>>2);
                int g  = (lane&3) ^ ((r_>>1)&3);
                load_lds16(v_g + (size_t)r_*HW_ + j0 + g*8, &s_v[buf][r0*32]);
            }
        }
    };

    stage(0, jbase);
    __syncthreads();

    for (int it = 0; it < (HW_/JC_)/32; ++it) {
        const int cur = it & 1;
        if (it + 1 < (HW_/JC_)/32)
            stage(cur^1, jbase + (it+1)*32);   // prefetch flies across WHOLE iter

        bf16x8 vb0[4];                          // consumer pre-read (s2=0 frags)
        if (wm == 0) {
            // ---- phase 1 (producers): ST [32j x 32i], K=64 in 4 steps ----
            f32x16 st;
            #pragma unroll
            for (int r = 0; r < 16; ++r) st[r] = 0.f;
            __builtin_amdgcn_s_setprio(1);
            #pragma unroll
            for (int s = 0; s < 4; ++s) {
                int slot = (s*2 + h) ^ (c & 7);
                bf16x8 a1 = *(const bf16x8*)(&s_xq[cur][c*64 + slot*8]);
                st = __builtin_amdgcn_mfma_f32_32x32x16_bf16(a1, kb[s], st, 0, 0, 0);
            }
            __builtin_amdgcn_s_setprio(0);

            // exp + pack bf16x2
            unsigned int dq[8];
            #pragma unroll
            for (int qd = 0; qd < 8; ++qd) {
                union { float f; unsigned int u; } ua, ub;
                float e0 = __expf(st[2*qd]);
                float e1 = __expf(st[2*qd+1]);
                lp += e0 + e1;
                ua.f = e0; ub.f = e1;
                dq[qd] = __builtin_amdgcn_perm(ub.u, ua.u, 0x07060302);
            }

            // j-half exchange in-register (permlane32_swap; R9-verified table)
            U4 a2[2];
            {
                u32x2 r02 = __builtin_amdgcn_permlane32_swap(dq[0], dq[2], false, false);
                u32x2 r13 = __builtin_amdgcn_permlane32_swap(dq[1], dq[3], false, false);
                u32x2 r46 = __builtin_amdgcn_permlane32_swap(dq[4], dq[6], false, false);
                u32x2 r57 = __builtin_amdgcn_permlane32_swap(dq[5], dq[7], false, false);
                a2[0].u[0] = r02[0]; a2[0].u[1] = r13[0];
                a2[0].u[2] = r02[1]; a2[0].u[3] = r13[1];
                a2[1].u[0] = r46[0]; a2[1].u[1] = r57[0];
                a2[1].u[2] = r46[1]; a2[1].u[3] = r57[1];
            }

            // publish P operand (lane-linear, q-XOR slot => 2-way/free banks)
            *(bf16x8*)(&s_p[wi][lane*16 + q*8])     = a2[0].v;
            *(bf16x8*)(&s_p[wi][lane*16 + (1^q)*8]) = a2[1].v;
            asm volatile("s_waitcnt lgkmcnt(0)" ::: "memory");  // P visible (LDS only)
            __builtin_amdgcn_sched_barrier(0);
            __builtin_amdgcn_s_barrier();                       // barrier #1
            asm volatile("" ::: "memory");

            // ---- phase 2 (producers): PV with in-reg a2, m rows 0..127 ----
            __builtin_amdgcn_s_setprio(1);
            #pragma unroll
            for (int s2 = 0; s2 < 2; ++s2) {
                #pragma unroll
                for (int mt = 0; mt < 4; ++mt) {
                    int rowm = mt*32 + c;
                    int slot = (s2*2 + h) ^ ((rowm>>1)&3);
                    bf16x8 vb = *(const bf16x8*)(&s_v[cur][rowm*32 + slot*8]);
                    acc[mt] = __builtin_amdgcn_mfma_f32_32x32x16_bf16(a2[s2].v, vb, acc[mt], 0, 0, 0);
                }
            }
            __builtin_amdgcn_s_setprio(0);
        } else {
            // ---- phase 1 (consumers): pre-read s2=0 V frags, rows 128..255
            #pragma unroll
            for (int mt = 0; mt < 4; ++mt) {
                int rowm = 128 + mt*32 + c;
                int slot = (0*2 + h) ^ ((rowm>>1)&3);
                vb0[mt] = *(const bf16x8*)(&s_v[cur][rowm*32 + slot*8]);
            }
            __builtin_amdgcn_sched_barrier(0);
            __builtin_amdgcn_s_barrier();                       // barrier #1
            asm volatile("" ::: "memory");

            // ---- phase 2 (consumers): PV from shared P ----
            U4 a2c[2];
            a2c[0].v = *(const bf16x8*)(&s_p[wi][lane*16 + q*8]);
            a2c[1].v = *(const bf16x8*)(&s_p[wi][lane*16 + (1^q)*8]);
            __builtin_amdgcn_s_setprio(1);
            #pragma unroll
            for (int mt = 0; mt < 4; ++mt)
                acc[mt] = __builtin_amdgcn_mfma_f32_32x32x16_bf16(a2c[0].v, vb0[mt], acc[mt], 0, 0, 0);
            #pragma unroll
            for (int mt = 0; mt < 4; ++mt) {
                int rowm = 128 + mt*32 + c;
                int slot = (1*2 + h) ^ ((rowm>>1)&3);
                bf16x8 vb = *(const bf16x8*)(&s_v[cur][rowm*32 + slot*8]);
                acc[mt] = __builtin_amdgcn_mfma_f32_32x32x16_bf16(a2c[1].v, vb, acc[mt], 0, 0, 0);
            }
            __builtin_amdgcn_s_setprio(0);
        }

        __syncthreads();   // barrier #2: drains prefetch vmcnt + buffer swap
    }

    // l partials (producers; mgp==0 single-writer per (jc,b,i))
    float l = lp + __shfl_xor(lp, 32, 64);
    if (wm == 0 && h == 0 && mgp == 0)
        lw[(size_t)(jc*B_ + b)*HW_ + i0 + c] = l;

    // partial O (unnormalized) -> bf16 workspace [jc][b][m][i]
    const size_t opb = ((size_t)(jc*B_ + b)*M_ + mgp*256 + wm*128)*HW_;
    #pragma unroll
    for (int mt = 0; mt < 4; ++mt) {
        size_t rb = opb + (size_t)(mt*32 + c)*HW_ + i0;
        #pragma unroll
        for (int g = 0; g < 4; ++g) {
            ushort4 s4;
            s4.x = f2bfu(acc[mt][4*g+0]);
            s4.y = f2bfu(acc[mt][4*g+1]);
            s4.z = f2bfu(acc[mt][4*g+2]);
            s4.w = f2bfu(acc[mt][4*g+3]);
            *(ushort4*)(Op + rb + 8*g + 4*h) = s4;
        }
    }
}

// ---------------------------------------------------------------------------
// Kernel 3: combine j-split partials + residual epilogue. (VERBATIM R7.)
// ---------------------------------------------------------------------------
__global__ __launch_bounds__(256) void reduce_kernel(
    const float* __restrict__ x, const float* __restrict__ gamma_p,
    const unsigned short* __restrict__ Op, const float* __restrict__ lw,
    float* __restrict__ out)
{
    size_t idx = ((size_t)blockIdx.x*256 + threadIdx.x)*4;  // flat [b][m][i]
    int i = idx & (HW_-1);
    size_t bm = idx >> 12;
    int m = bm & (M_-1);
    int b = (int)(bm >> 9);

    float4 o = {0.f,0.f,0.f,0.f};
    float4 l = {0.f,0.f,0.f,0.f};
    #pragma unroll
    for (int jc = 0; jc < JC_; ++jc) {
        ushort4 ov = *(const ushort4*)(Op + ((size_t)(jc*B_ + b)*M_ + m)*HW_ + i);
        o.x += __uint_as_float((unsigned int)ov.x << 16);
        o.y += __uint_as_float((unsigned int)ov.y << 16);
        o.z += __uint_as_float((unsigned int)ov.z << 16);
        o.w += __uint_as_float((unsigned int)ov.w << 16);
        float4 lv = *(const float4*)(lw + (size_t)(jc*B_ + b)*HW_ + i);
        l.x += lv.x; l.y += lv.y; l.z += lv.z; l.w += lv.w;
    }
    const float gamma = gamma_p[0];
    float4 xv = *(const float4*)(x + idx);
    float4 r;
    r.x = gamma*xv.x + o.x / l.x;
    r.y = gamma*xv.y + o.y / l.y;
    r.z = gamma*xv.z + o.z / l.z;
    r.w = gamma*xv.w + o.w / l.w;
    *(float4*)(out + idx) = r;
}

// ---------------------------------------------------------------------------
extern "C" void kernel_launch(void* const* d_in, const int* in_sizes, int n_in,
                              void* d_out, int out_size, void* d_ws, size_t ws_size,
                              hipStream_t stream)
{
    const float* x     = (const float*)d_in[0];
    const float* Wk    = (const float*)d_in[1];
    const float* bk    = (const float*)d_in[2];
    const float* Wq    = (const float*)d_in[3];
    const float* bq    = (const float*)d_in[4];
    const float* Wv    = (const float*)d_in[5];
    const float* bv    = (const float*)d_in[6];
    const float* gamma = (const float*)d_in[7];
    float* out = (float*)d_out;

    char* ws = (char*)d_ws;
    short*          xk   = (short*)(ws);                            // 1 MB
    short*          xq   = (short*)(ws + (1<<20));                  // 1 MB
    short*          v    = (short*)(ws + (2<<20));                  // 8 MB
    unsigned short* Op   = (unsigned short*)(ws + (10<<20) + 8192); // 32 MB
    float*          lw   = (float*)(ws + (10<<20) + 8192
                                    + (size_t)JC_*B_*M_*HW_*2);     // 128 KB

    proj_kernel<<<B_*(D_/4)*(HW_/32), 256, 0, stream>>>(x, Wk, bk, Wq, bq, Wv, bv,
                                                        xk, xq, (__hip_bfloat16*)v);
    attn_kernel<<<8*64, 512, 0, stream>>>(xk, xq, v, Op, lw);
    reduce_kernel<<<(B_*M_*HW_)/(256*4), 256, 0, stream>>>(x, gamma, Op, lw, out);
}

// Round 6
// 160.643 us; speedup vs baseline: 1.2147x; 1.2147x over previous
//
#include <hip/hip_runtime.h>
#include <hip/hip_bf16.h>

// Problem constants
#define B_   2
#define C_   32
#define D_   16
#define HW_  4096
#define CK_  4
#define E_   64    // CK_*D_  (qk dim)
#define M_   512   // C_*D_   (v dim)
#define JC_  4     // j-split factor (flash split-K)

typedef __attribute__((ext_vector_type(8)))  short bf16x8;
typedef __attribute__((ext_vector_type(16))) float f32x16;
typedef __attribute__((ext_vector_type(2)))  unsigned int u32x2;

union U4 { unsigned int u[4]; bf16x8 v; };

__device__ __forceinline__ short f2bf(float f) {
    __hip_bfloat16 h = __float2bfloat16(f);
    return *reinterpret_cast<short*>(&h);
}
__device__ __forceinline__ unsigned short f2bfu(float f) {
    __hip_bfloat16 h = __float2bfloat16(f);
    return *reinterpret_cast<unsigned short*>(&h);
}

// ---------------------------------------------------------------------------
// Kernel 1: MFMA projections (folded-prep version, harness-verified R12).
// Weight fragments + biases loaded directly from raw f32 tensors (5 KB,
// L2-hot). Math identical to the original Wall path.
// ---------------------------------------------------------------------------
__global__ __launch_bounds__(256) void proj_kernel(
    const float* __restrict__ x,
    const float* __restrict__ Wk, const float* __restrict__ bk,
    const float* __restrict__ Wq, const float* __restrict__ bq,
    const float* __restrict__ Wv, const float* __restrict__ bv,
    short* __restrict__ xk, short* __restrict__ xq,
    __hip_bfloat16* __restrict__ v)
{
    __shared__ short s_k[32*16], s_q[32*16];   // [p 32][w*4+o' 16]
    const int t    = threadIdx.x;
    const int lane = t & 63;
    const int w    = t >> 6;
    const int h    = lane >> 5;
    const int c    = lane & 31;

    const int pt = blockIdx.x & 127;
    const int dg = (blockIdx.x >> 7) & 3;
    const int b  = blockIdx.x >> 9;
    const int d  = dg*4 + w;
    const int p0 = pt*32;

    bf16x8 af[2][2];
    #pragma unroll
    for (int s = 0; s < 2; ++s) {
        const float* wv = Wv + c*C_ + s*16 + h*8;
        #pragma unroll
        for (int k = 0; k < 8; ++k) af[0][s][k] = f2bf(wv[k]);
        const float* wu = (c < 4) ? (Wk + c*C_ + s*16 + h*8)
                        : (c < 8) ? (Wq + (c-4)*C_ + s*16 + h*8) : nullptr;
        #pragma unroll
        for (int k = 0; k < 8; ++k) af[1][s][k] = f2bf(wu ? wu[k] : 0.f);
    }

    U4 xb[2];
    #pragma unroll
    for (int s = 0; s < 2; ++s) {
        #pragma unroll
        for (int j = 0; j < 4; ++j) {
            int c0 = s*16 + h*8 + 2*j;
            union { float f; unsigned int u; } ua, ub;
            ua.f = x[(((size_t)(b*C_ + c0  )*D_ + d)*HW_) + p0 + c];
            ub.f = x[(((size_t)(b*C_ + c0+1)*D_ + d)*HW_) + p0 + c];
            xb[s].u[j] = __builtin_amdgcn_perm(ub.u, ua.u, 0x07060302);
        }
    }

    f32x16 a0, a1;
    #pragma unroll
    for (int r = 0; r < 16; ++r) { a0[r] = 0.f; a1[r] = 0.f; }
    #pragma unroll
    for (int s = 0; s < 2; ++s) {
        a0 = __builtin_amdgcn_mfma_f32_32x32x16_bf16(af[0][s], xb[s].v, a0, 0, 0, 0);
        a1 = __builtin_amdgcn_mfma_f32_32x32x16_bf16(af[1][s], xb[s].v, a1, 0, 0, 0);
    }

    #pragma unroll
    for (int r = 0; r < 16; ++r) {
        int o = (r & 3) + 8*(r >> 2) + 4*h;
        v[((size_t)b*M_ + (o*D_ + d))*HW_ + p0 + c] = __float2bfloat16(a0[r] + bv[o]);
    }

    #pragma unroll
    for (int r = 0; r < 4; ++r) {
        if (h == 0) s_k[c*16 + w*4 + r] = f2bf(a1[r] + bk[r]);
        else        s_q[c*16 + w*4 + r] = f2bf(a1[r] + bq[r]);
    }
    __syncthreads();

    const int p = t >> 3, seg = t & 7;
    size_t gb = ((size_t)b*HW_ + p0 + p)*E_ + dg*16 + seg*2;
    *(unsigned int*)(xk + gb) = *(const unsigned int*)(&s_k[p*16 + seg*2]);
    *(unsigned int*)(xq + gb) = *(const unsigned int*)(&s_q[p*16 + seg*2]);
}

// ---------------------------------------------------------------------------
// Kernel 2: flash attention, split-K (JC_=4), V staged in LDS.
//  R14 == R9 attn VERBATIM (70.68 µs, session-best). No setprio (measured
//  +1.1 µs in R12 — lockstep loop has no wave role diversity, m190 pattern).
//  No producer/consumer split (R13: −32 µs — critical path unchanged, half
//  the waves idled, traffic tripled). No cross-block fused tail (R11:
//  device-scope fences = full-L2 writeback/invalidate on chiplet arch).
//  Per-wave 32 i-rows (acc[4] = 64 regs) -> 4 blocks/CU (R9's occupancy
//  gain); permlane32_swap j-half exchange (off the LDS pipe); R7 swizzles.
//  Note: remaining 6.3M LDS bank-conflict cycles are structural — both LDS
//  tiles have <=128 B rows, so a 64-lane ds_read_b128 must alias the 128 B
//  bank array >=8x regardless of swizzle (pigeonhole).
// ---------------------------------------------------------------------------
__device__ __forceinline__ void load_lds16(const short* g, short* l) {
    __builtin_amdgcn_global_load_lds((const __attribute__((address_space(1))) void*)g,
                                     (__attribute__((address_space(3))) void*)l,
                                     16, 0, 0);
}

__global__ __launch_bounds__(256, 4) void attn_kernel(
    const short* __restrict__ xk_, const short* __restrict__ xq_,
    const short* __restrict__ v_,
    unsigned short* __restrict__ Op, float* __restrict__ lw)
{
    __shared__ short s_xq[2][2048];          // XQ tile: 32 j x 64 e      (8 KB)
    __shared__ short s_v [2][4096];          // V  tile: 128 m x 32 j     (16 KB)

    const int t    = threadIdx.x;
    const int lane = t & 63;
    const int w    = t >> 6;
    const int h    = lane >> 5;
    const int c    = lane & 31;

    const int cls  = blockIdx.x & 7;         // constant per XCD under %8 mapping
    const int b    = cls >> 2, mg = cls & 3;
    const int rest = blockIdx.x >> 3;
    const int ig   = rest & 31;              // 32 i-groups of 128 rows
    const int jc   = rest >> 5;
    const int i0   = ig*128 + w*32;          // wave's 32-row i-tile
    const int jbase = jc*(HW_/JC_);          // 1024-wide j chunk

    const short* xk_g = xk_ + (size_t)b*HW_*E_;
    const short* xq_g = xq_ + (size_t)b*HW_*E_;
    const short* v_g  = v_  + (size_t)b*M_*HW_ + (size_t)mg*128*HW_;

    // XK B-frags: kb[s] = XK[i0+c][e = s*16 + h*8 ..+7]
    bf16x8 kb[4];
    #pragma unroll
    for (int s = 0; s < 4; ++s)
        kb[s] = *(const bf16x8*)(xk_g + (size_t)(i0 + c)*E_ + s*16 + h*8);

    f32x16 acc[4];
    #pragma unroll
    for (int mt = 0; mt < 4; ++mt)
        #pragma unroll
        for (int r = 0; r < 16; ++r) acc[mt][r] = 0.f;
    float lp = 0.f;

    // ---- staging (VERBATIM R7 swizzles) ----
    auto stage = [&](int buf, int j0) {
        {
            int r_ = w*8 + (lane>>3), cc = (lane&7) ^ (r_&7);
            load_lds16(xq_g + (size_t)(j0 + r_)*E_ + cc*8, &s_xq[buf][w*512]);
        }
        #pragma unroll
        for (int k = 0; k < 2; ++k) {
            int r0 = w*32 + k*16;
            int r_ = r0 + (lane>>2);
            int g  = (lane&3) ^ ((r_>>1)&3);
            load_lds16(v_g + (size_t)r_*HW_ + j0 + g*8, &s_v[buf][r0*32]);
        }
    };

    stage(0, jbase);
    __syncthreads();

    for (int it = 0; it < (HW_/JC_)/32; ++it) {
        const int cur = it & 1;
        if (it + 1 < (HW_/JC_)/32)
            stage(cur^1, jbase + (it+1)*32);   // prefetch flies during compute

        // ST [32j x 32i], K=64 in 4 steps
        f32x16 st;
        #pragma unroll
        for (int r = 0; r < 16; ++r) st[r] = 0.f;
        #pragma unroll
        for (int s = 0; s < 4; ++s) {
            int slot = (s*2 + h) ^ (c & 7);
            bf16x8 a1 = *(const bf16x8*)(&s_xq[cur][c*64 + slot*8]);
            st = __builtin_amdgcn_mfma_f32_32x32x16_bf16(a1, kb[s], st, 0, 0, 0);
        }

        // exp + pack bf16x2
        unsigned int dq[8];
        #pragma unroll
        for (int qd = 0; qd < 8; ++qd) {
            union { float f; unsigned int u; } ua, ub;
            float e0 = __expf(st[2*qd]);
            float e1 = __expf(st[2*qd+1]);
            lp += e0 + e1;
            ua.f = e0; ub.f = e1;
            dq[qd] = __builtin_amdgcn_perm(ub.u, ua.u, 0x07060302);
        }

        // j-half exchange in-register: swap(d,s) -> {lo:d.lo,hi:s.lo},
        // {lo:d.hi,hi:s.hi} == the a2 words (h?pd[k]:dq[k'] table of R8)
        U4 a2[2];
        {
            u32x2 r02 = __builtin_amdgcn_permlane32_swap(dq[0], dq[2], false, false);
            u32x2 r13 = __builtin_amdgcn_permlane32_swap(dq[1], dq[3], false, false);
            u32x2 r46 = __builtin_amdgcn_permlane32_swap(dq[4], dq[6], false, false);
            u32x2 r57 = __builtin_amdgcn_permlane32_swap(dq[5], dq[7], false, false);
            a2[0].u[0] = r02[0]; a2[0].u[1] = r13[0];
            a2[0].u[2] = r02[1]; a2[0].u[3] = r13[1];
            a2[1].u[0] = r46[0]; a2[1].u[1] = r57[0];
            a2[1].u[2] = r46[1]; a2[1].u[3] = r57[1];
        }

        // PV: 2 K-steps x 4 m-tiles
        #pragma unroll
        for (int s2 = 0; s2 < 2; ++s2) {
            #pragma unroll
            for (int mt = 0; mt < 4; ++mt) {
                int rowm = mt*32 + c;
                int slot = (s2*2 + h) ^ ((rowm>>1)&3);
                bf16x8 vb = *(const bf16x8*)(&s_v[cur][rowm*32 + slot*8]);
                acc[mt] = __builtin_amdgcn_mfma_f32_32x32x16_bf16(a2[s2].v, vb, acc[mt], 0, 0, 0);
            }
        }
        __syncthreads();                     // drains prefetch + buffer swap
    }

    // l partials: sum two j-halves; one writer per (jc,b,i)
    float l = lp + __shfl_xor(lp, 32, 64);
    if (h == 0 && mg == 0)
        lw[(size_t)(jc*B_ + b)*HW_ + i0 + c] = l;

    // partial O (unnormalized) -> bf16 workspace [jc][b][m][i]
    const size_t opb = ((size_t)(jc*B_ + b)*M_ + mg*128)*HW_;
    #pragma unroll
    for (int mt = 0; mt < 4; ++mt) {
        size_t rb = opb + (size_t)(mt*32 + c)*HW_ + i0;
        #pragma unroll
        for (int g = 0; g < 4; ++g) {
            ushort4 s4;
            s4.x = f2bfu(acc[mt][4*g+0]);
            s4.y = f2bfu(acc[mt][4*g+1]);
            s4.z = f2bfu(acc[mt][4*g+2]);
            s4.w = f2bfu(acc[mt][4*g+3]);
            *(ushort4*)(Op + rb + 8*g + 4*h) = s4;
        }
    }
}

// ---------------------------------------------------------------------------
// Kernel 3: combine j-split partials + residual epilogue. (VERBATIM R7.)
// ---------------------------------------------------------------------------
__global__ __launch_bounds__(256) void reduce_kernel(
    const float* __restrict__ x, const float* __restrict__ gamma_p,
    const unsigned short* __restrict__ Op, const float* __restrict__ lw,
    float* __restrict__ out)
{
    size_t idx = ((size_t)blockIdx.x*256 + threadIdx.x)*4;  // flat [b][m][i]
    int i = idx & (HW_-1);
    size_t bm = idx >> 12;
    int m = bm & (M_-1);
    int b = (int)(bm >> 9);

    float4 o = {0.f,0.f,0.f,0.f};
    float4 l = {0.f,0.f,0.f,0.f};
    #pragma unroll
    for (int jc = 0; jc < JC_; ++jc) {
        ushort4 ov = *(const ushort4*)(Op + ((size_t)(jc*B_ + b)*M_ + m)*HW_ + i);
        o.x += __uint_as_float((unsigned int)ov.x << 16);
        o.y += __uint_as_float((unsigned int)ov.y << 16);
        o.z += __uint_as_float((unsigned int)ov.z << 16);
        o.w += __uint_as_float((unsigned int)ov.w << 16);
        float4 lv = *(const float4*)(lw + (size_t)(jc*B_ + b)*HW_ + i);
        l.x += lv.x; l.y += lv.y; l.z += lv.z; l.w += lv.w;
    }
    const float gamma = gamma_p[0];
    float4 xv = *(const float4*)(x + idx);
    float4 r;
    r.x = gamma*xv.x + o.x / l.x;
    r.y = gamma*xv.y + o.y / l.y;
    r.z = gamma*xv.z + o.z / l.z;
    r.w = gamma*xv.w + o.w / l.w;
    *(float4*)(out + idx) = r;
}

// ---------------------------------------------------------------------------
extern "C" void kernel_launch(void* const* d_in, const int* in_sizes, int n_in,
                              void* d_out, int out_size, void* d_ws, size_t ws_size,
                              hipStream_t stream)
{
    const float* x     = (const float*)d_in[0];
    const float* Wk    = (const float*)d_in[1];
    const float* bk    = (const float*)d_in[2];
    const float* Wq    = (const float*)d_in[3];
    const float* bq    = (const float*)d_in[4];
    const float* Wv    = (const float*)d_in[5];
    const float* bv    = (const float*)d_in[6];
    const float* gamma = (const float*)d_in[7];
    float* out = (float*)d_out;

    char* ws = (char*)d_ws;
    short*          xk   = (short*)(ws);                            // 1 MB
    short*          xq   = (short*)(ws + (1<<20));                  // 1 MB
    short*          v    = (short*)(ws + (2<<20));                  // 8 MB
    unsigned short* Op   = (unsigned short*)(ws + (10<<20) + 8192); // 32 MB
    float*          lw   = (float*)(ws + (10<<20) + 8192
                                    + (size_t)JC_*B_*M_*HW_*2);     // 128 KB

    proj_kernel<<<B_*(D_/4)*(HW_/32), 256, 0, stream>>>(x, Wk, bk, Wq, bq, Wv, bv,
                                                        xk, xq, (__hip_bfloat16*)v);
    attn_kernel<<<8*32*JC_, 256, 0, stream>>>(xk, xq, v, Op, lw);
    reduce_kernel<<<(B_*M_*HW_)/(256*4), 256, 0, stream>>>(x, gamma, Op, lw, out);
}